// Round 1
// baseline (396.928 us; speedup 1.0000x reference)
//
#include <hip/hip_runtime.h>
#include <stdint.h>

// Problem constants (fixed by reference)
#define NB 8
#define NH 12
#define NLQ 32
#define NLF 256
#define NV 32000
#define NS 4
#define NV4 (NV / 4)   /* 8000 float4 per [b] row */

// f-row split factor: 4 partial blocks per (c4-tile, b).
// Geometry: 32*8*4 = 1024 blocks = 4096 waves = 4 waves/SIMD (was 1/SIMD).
#define PSPLIT 4
#define FCHUNK (NLF / PSPLIT)   /* 64 f rows per partial block */
#define QCHUNK (NLQ / PSPLIT)   /* 8 q rows per partial block */

// d_out layout: values[NS,NB,NV] | logprobs[NS,NB] | actions[NS,NB,NLF]
#define OUT_LOGP (NS * NB * NV)          /* 1024000 */
#define OUT_ACT  (OUT_LOGP + NS * NB)    /* 1024032 */

__device__ __forceinline__ uint32_t rotl32(uint32_t v, int r) {
  return (v << r) | (v >> (32 - r));
}

// Exact JAX threefry2x32 (rotations [13,15,26,6]/[17,29,16,24], 5 key injections)
__device__ __forceinline__ void threefry2x32(uint32_t k0, uint32_t k1,
                                             uint32_t& x0, uint32_t& x1) {
  const uint32_t ks2 = k0 ^ k1 ^ 0x1BD11BDAu;
  x0 += k0; x1 += k1;
#define TF_ROUND(r) { x0 += x1; x1 = rotl32(x1, r); x1 ^= x0; }
  TF_ROUND(13) TF_ROUND(15) TF_ROUND(26) TF_ROUND(6)
  x0 += k1; x1 += ks2 + 1u;
  TF_ROUND(17) TF_ROUND(29) TF_ROUND(16) TF_ROUND(24)
  x0 += ks2; x1 += k0 + 2u;
  TF_ROUND(13) TF_ROUND(15) TF_ROUND(26) TF_ROUND(6)
  x0 += k0; x1 += k1 + 3u;
  TF_ROUND(17) TF_ROUND(29) TF_ROUND(16) TF_ROUND(24)
  x0 += k1; x1 += ks2 + 4u;
  TF_ROUND(13) TF_ROUND(15) TF_ROUND(26) TF_ROUND(6)
  x0 += ks2; x1 += k0 + 5u;
#undef TF_ROUND
}

// ---------- Kernel 1: mean over heads -> ws_scores[B,LQ,LF] ----------
__global__ __launch_bounds__(256) void k_mean(const float* __restrict__ as,
                                              float* __restrict__ scores) {
  const int o = blockIdx.x * 256 + threadIdx.x;   // [0, 65536)
  const int f  = o & (NLF - 1);
  const int lq = (o >> 8) & (NLQ - 1);
  const int b  = o >> 13;
  float s = 0.f;
#pragma unroll
  for (int h = 0; h < NH; ++h)
    s += as[(((size_t)(b * NH + h) * NLQ) + lq) * NLF + f];
  scores[o] = s / 12.0f;
}

// ---------- Kernel 2: probs, threefry actions, logprobs ----------
__global__ __launch_bounds__(256) void k_probs(
    const float* __restrict__ scores,      // ws [B,LQ,LF]
    const float* __restrict__ attn_mask,   // [B,LF]
    float* __restrict__ out,               // d_out base
    unsigned* __restrict__ actmask)        // ws [B,LF], bit s = action[s,b,f]
{
  const int b = blockIdx.x;
  const int f = threadIdx.x;

  float agg = -INFINITY;
#pragma unroll
  for (int lq = 0; lq < NLQ; ++lq)
    agg = fmaxf(agg, scores[(b * NLQ + lq) * NLF + f]);

  const float amask = attn_mask[b * NLF + f];
  const float p = amask * (1.0f / (1.0f + expf(-agg)));   // sigmoid * mask

  const float lp  = logf(p);       // used only when action==1 (p>0 then)
  const float l1p = log1pf(-p);

  unsigned mask = 0;
  float terms[NS];
#pragma unroll
  for (int s = 0; s < NS; ++s) {
    bool act;
    if (s < NS - 1) {
      // JAX partitionable threefry 32-bit bits: counter n (u64),
      // (o0,o1) = threefry2x32(key, hi(n)=0, lo(n)=n); bits = o0 ^ o1
      const uint32_t n = (uint32_t)(s * (NB * NLF) + b * NLF + f);
      uint32_t x0 = 0u, x1 = n;
      threefry2x32(0u, 42u, x0, x1);
      const uint32_t bits = x0 ^ x1;
      const float u = __uint_as_float((bits >> 9) | 0x3f800000u) - 1.0f;
      act = (u < p);
    } else {
      act = (p >= 0.5f);
    }
    if (act) mask |= (1u << s);
    terms[s] = act ? lp : l1p;
    out[OUT_ACT + (s * NB + b) * NLF + f] = act ? 1.0f : 0.0f;
  }
  actmask[b * NLF + f] = mask;

  // block-reduce logprob terms over f for each s
  __shared__ float red[NS][NLF];
#pragma unroll
  for (int s = 0; s < NS; ++s) red[s][f] = terms[s];
  __syncthreads();
  for (int off = 128; off > 0; off >>= 1) {
    if (f < off) {
#pragma unroll
      for (int s = 0; s < NS; ++s) red[s][f] += red[s][f + off];
    }
    __syncthreads();
  }
  if (f == 0) {
#pragma unroll
    for (int s = 0; s < NS; ++s) out[OUT_LOGP + s * NB + b] = red[s][0];
  }
}

// ---------- Kernel 3a: partial raw maxima over a 64-f-row + 8-q-row chunk ----
// Round-N theory: old k_values was 1024 waves total = 1 wave/SIMD (zero TLP);
// latency-bound, not BW-bound. P=4 split -> 4096 waves = 4 waves/SIMD for the
// kernel moving 295/300 MB. Raw (pre-log1p) maxima are exact to propagate:
// max(log1p(relu(a)), log1p(relu(b))) == log1p(relu(max(a,b))) (monotone).
// Inner loops stay BRANCHLESS (fminf select with +/-INF) and loads manually
// batched 8-deep (round-3 post-mortem: per-f `if` serialized loads).
__global__ __launch_bounds__(256) void k_values_part(
    const float* __restrict__ q_logits,   // [B,LQ,V]
    const float* __restrict__ f_logits,   // [B,LF,V]
    const float* __restrict__ q_mask,     // [B,LQ]
    const unsigned* __restrict__ actmask, // ws [B,LF]
    float* __restrict__ part)             // ws [P][NS][NB][NV] raw maxima
{
  const int b = blockIdx.y;
  const int p = blockIdx.z;
  const int tid = threadIdx.x;

  // ssel[s][f] = +INF if action s selects row (p*FCHUNK+f) else -INF
  __shared__ float ssel[NS][FCHUNK];
  __shared__ float sqsel[QCHUNK];
  if (tid < FCHUNK) {
    const unsigned mk = actmask[b * NLF + p * FCHUNK + tid];
#pragma unroll
    for (int s = 0; s < NS; ++s)
      ssel[s][tid] = (mk >> s) & 1u ? INFINITY : -INFINITY;
  }
  if (tid < QCHUNK)
    sqsel[tid] = (q_mask[b * NLQ + p * QCHUNK + tid] > 0.5f) ? INFINITY
                                                             : -INFINITY;
  __syncthreads();

  const int c4 = blockIdx.x * 256 + tid;      // float4 index within row
  if (c4 >= NV4) return;

  const float4* qp = (const float4*)q_logits;
  const float4* fp = (const float4*)f_logits;

  float m[NS][4];
#pragma unroll
  for (int s = 0; s < NS; ++s)
#pragma unroll
    for (int c = 0; c < 4; ++c) m[s][c] = -INFINITY;

  // ---- q share of this p-block: 8 rows, one 8-deep batch, folded into all s
  {
    float4 x[8];
#pragma unroll
    for (int j = 0; j < 8; ++j)
      x[j] = qp[(size_t)(b * NLQ + p * QCHUNK + j) * NV4 + c4];
    float qm[4] = {-INFINITY, -INFINITY, -INFINITY, -INFINITY};
#pragma unroll
    for (int j = 0; j < 8; ++j) {
      const float sv = sqsel[j];
      qm[0] = fmaxf(qm[0], fminf(x[j].x, sv));
      qm[1] = fmaxf(qm[1], fminf(x[j].y, sv));
      qm[2] = fmaxf(qm[2], fminf(x[j].z, sv));
      qm[3] = fmaxf(qm[3], fminf(x[j].w, sv));
    }
#pragma unroll
    for (int s = 0; s < NS; ++s)
#pragma unroll
      for (int c = 0; c < 4; ++c) m[s][c] = fmaxf(m[s][c], qm[c]);
  }

  // ---- f share: 64 rows, 8 batches of 8, branchless 4-sample select/max
  for (int f0 = 0; f0 < FCHUNK; f0 += 8) {
    float4 x[8];
#pragma unroll
    for (int j = 0; j < 8; ++j)
      x[j] = fp[(size_t)(b * NLF + p * FCHUNK + f0 + j) * NV4 + c4];
#pragma unroll
    for (int j = 0; j < 8; ++j) {
#pragma unroll
      for (int s = 0; s < NS; ++s) {
        const float sv = ssel[s][f0 + j];
        m[s][0] = fmaxf(m[s][0], fminf(x[j].x, sv));
        m[s][1] = fmaxf(m[s][1], fminf(x[j].y, sv));
        m[s][2] = fmaxf(m[s][2], fminf(x[j].z, sv));
        m[s][3] = fmaxf(m[s][3], fminf(x[j].w, sv));
      }
    }
  }

  float4* pp = (float4*)part;
#pragma unroll
  for (int s = 0; s < NS; ++s) {
    float4 r;
    r.x = m[s][0]; r.y = m[s][1]; r.z = m[s][2]; r.w = m[s][3];
    pp[((size_t)(p * NS + s) * NB + b) * NV4 + c4] = r;
  }
}

// ---------- Kernel 3b: finalize — max over P partials, log1p(relu) once ----
// Only ~20 MB of traffic (16.4 read + 4.1 write); 1 wave/SIMD geometry is
// fine here since the 16 partial loads per thread are all independent (ILP).
__global__ __launch_bounds__(256) void k_finalize(
    const float* __restrict__ part,       // ws [P][NS][NB][NV]
    float* __restrict__ out)              // d_out base (values at offset 0)
{
  const int b = blockIdx.y;
  const int tid = threadIdx.x;
  const int c4 = blockIdx.x * 256 + tid;
  if (c4 >= NV4) return;

  const float4* pp = (const float4*)part;
  float4* ov = (float4*)out;

  // load all 16 partials up front (independent loads stay in flight)
  float4 t[PSPLIT][NS];
#pragma unroll
  for (int p = 0; p < PSPLIT; ++p)
#pragma unroll
    for (int s = 0; s < NS; ++s)
      t[p][s] = pp[((size_t)(p * NS + s) * NB + b) * NV4 + c4];

#pragma unroll
  for (int s = 0; s < NS; ++s) {
    float4 mm = t[0][s];
#pragma unroll
    for (int p = 1; p < PSPLIT; ++p) {
      mm.x = fmaxf(mm.x, t[p][s].x);
      mm.y = fmaxf(mm.y, t[p][s].y);
      mm.z = fmaxf(mm.z, t[p][s].z);
      mm.w = fmaxf(mm.w, t[p][s].w);
    }
    float4 r;
    r.x = log1pf(fmaxf(mm.x, 0.f));
    r.y = log1pf(fmaxf(mm.y, 0.f));
    r.z = log1pf(fmaxf(mm.z, 0.f));
    r.w = log1pf(fmaxf(mm.w, 0.f));
    ov[(size_t)(s * NB + b) * NV4 + c4] = r;
  }
}

extern "C" void kernel_launch(void* const* d_in, const int* in_sizes, int n_in,
                              void* d_out, int out_size, void* d_ws, size_t ws_size,
                              hipStream_t stream) {
  const float* attn_scores = (const float*)d_in[0];
  const float* q_logits    = (const float*)d_in[1];
  const float* f_logits    = (const float*)d_in[2];
  const float* q_mask      = (const float*)d_in[3];
  const float* attn_mask   = (const float*)d_in[4];
  float* out = (float*)d_out;

  float* ws_scores   = (float*)d_ws;                              // B*LQ*LF f32
  unsigned* ws_mask  = (unsigned*)(ws_scores + NB * NLQ * NLF);   // B*LF u32
  float* ws_part     = (float*)(ws_mask + NB * NLF);              // P*NS*NB*NV f32 (16.4 MB, 16B-aligned)

  k_mean<<<dim3((NB * NLQ * NLF) / 256), 256, 0, stream>>>(attn_scores, ws_scores);
  k_probs<<<dim3(NB), 256, 0, stream>>>(ws_scores, attn_mask, out, ws_mask);
  k_values_part<<<dim3((NV4 + 255) / 256, NB, PSPLIT), 256, 0, stream>>>(
      q_logits, f_logits, q_mask, ws_mask, ws_part);
  k_finalize<<<dim3((NV4 + 255) / 256, NB), 256, 0, stream>>>(ws_part, out);
}

// Round 3
// 392.407 us; speedup vs baseline: 1.0115x; 1.0115x over previous
//
#include <hip/hip_runtime.h>
#include <stdint.h>

// Problem constants (fixed by reference)
#define NB 8
#define NH 12
#define NLQ 32
#define NLF 256
#define NV 32000
#define NS 4
#define NV4 (NV / 4)   /* 8000 float4 per [b] row */

// In-block f-split: 1024-thread blocks, 4 quarter-parts of 256 threads.
// Each part covers 64 f rows + 8 q rows of the SAME 256-wide c4 tile;
// parts combine via LDS. 256 blocks = 1 block/CU = 4 waves/SIMD with
// ZERO extra HBM traffic (round-1 post-mortem: global partials cost
// +33 MB ≈ +8 us, exactly the measured regression).
#define NPART 4
#define FCHUNK (NLF / NPART)   /* 64 f rows per part */
#define QCHUNK (NLQ / NPART)   /* 8 q rows per part */

// d_out layout: values[NS,NB,NV] | logprobs[NS,NB] | actions[NS,NB,NLF]
#define OUT_LOGP (NS * NB * NV)          /* 1024000 */
#define OUT_ACT  (OUT_LOGP + NS * NB)    /* 1024032 */

__device__ __forceinline__ uint32_t rotl32(uint32_t v, int r) {
  return (v << r) | (v >> (32 - r));
}

// Exact JAX threefry2x32 (rotations [13,15,26,6]/[17,29,16,24], 5 key injections)
__device__ __forceinline__ void threefry2x32(uint32_t k0, uint32_t k1,
                                             uint32_t& x0, uint32_t& x1) {
  const uint32_t ks2 = k0 ^ k1 ^ 0x1BD11BDAu;
  x0 += k0; x1 += k1;
#define TF_ROUND(r) { x0 += x1; x1 = rotl32(x1, r); x1 ^= x0; }
  TF_ROUND(13) TF_ROUND(15) TF_ROUND(26) TF_ROUND(6)
  x0 += k1; x1 += ks2 + 1u;
  TF_ROUND(17) TF_ROUND(29) TF_ROUND(16) TF_ROUND(24)
  x0 += ks2; x1 += k0 + 2u;
  TF_ROUND(13) TF_ROUND(15) TF_ROUND(26) TF_ROUND(6)
  x0 += k0; x1 += k1 + 3u;
  TF_ROUND(17) TF_ROUND(29) TF_ROUND(16) TF_ROUND(24)
  x0 += k1; x1 += ks2 + 4u;
  TF_ROUND(13) TF_ROUND(15) TF_ROUND(26) TF_ROUND(6)
  x0 += ks2; x1 += k0 + 5u;
#undef TF_ROUND
}

// ---------- Kernel 1: mean over heads -> ws_scores[B,LQ,LF] ----------
__global__ __launch_bounds__(256) void k_mean(const float* __restrict__ as,
                                              float* __restrict__ scores) {
  const int o = blockIdx.x * 256 + threadIdx.x;   // [0, 65536)
  const int f  = o & (NLF - 1);
  const int lq = (o >> 8) & (NLQ - 1);
  const int b  = o >> 13;
  float s = 0.f;
#pragma unroll
  for (int h = 0; h < NH; ++h)
    s += as[(((size_t)(b * NH + h) * NLQ) + lq) * NLF + f];
  scores[o] = s / 12.0f;
}

// ---------- Kernel 2: probs, threefry actions, logprobs ----------
__global__ __launch_bounds__(256) void k_probs(
    const float* __restrict__ scores,      // ws [B,LQ,LF]
    const float* __restrict__ attn_mask,   // [B,LF]
    float* __restrict__ out,               // d_out base
    unsigned* __restrict__ actmask)        // ws [B,LF], bit s = action[s,b,f]
{
  const int b = blockIdx.x;
  const int f = threadIdx.x;

  float agg = -INFINITY;
#pragma unroll
  for (int lq = 0; lq < NLQ; ++lq)
    agg = fmaxf(agg, scores[(b * NLQ + lq) * NLF + f]);

  const float amask = attn_mask[b * NLF + f];
  const float p = amask * (1.0f / (1.0f + expf(-agg)));   // sigmoid * mask

  const float lp  = logf(p);       // used only when action==1 (p>0 then)
  const float l1p = log1pf(-p);

  unsigned mask = 0;
  float terms[NS];
#pragma unroll
  for (int s = 0; s < NS; ++s) {
    bool act;
    if (s < NS - 1) {
      // JAX partitionable threefry 32-bit bits: counter n (u64),
      // (o0,o1) = threefry2x32(key, hi(n)=0, lo(n)=n); bits = o0 ^ o1
      const uint32_t n = (uint32_t)(s * (NB * NLF) + b * NLF + f);
      uint32_t x0 = 0u, x1 = n;
      threefry2x32(0u, 42u, x0, x1);
      const uint32_t bits = x0 ^ x1;
      const float u = __uint_as_float((bits >> 9) | 0x3f800000u) - 1.0f;
      act = (u < p);
    } else {
      act = (p >= 0.5f);
    }
    if (act) mask |= (1u << s);
    terms[s] = act ? lp : l1p;
    out[OUT_ACT + (s * NB + b) * NLF + f] = act ? 1.0f : 0.0f;
  }
  actmask[b * NLF + f] = mask;

  // block-reduce logprob terms over f for each s
  __shared__ float red[NS][NLF];
#pragma unroll
  for (int s = 0; s < NS; ++s) red[s][f] = terms[s];
  __syncthreads();
  for (int off = 128; off > 0; off >>= 1) {
    if (f < off) {
#pragma unroll
      for (int s = 0; s < NS; ++s) red[s][f] += red[s][f + off];
    }
    __syncthreads();
  }
  if (f == 0) {
#pragma unroll
    for (int s = 0; s < NS; ++s) out[OUT_LOGP + s * NB + b] = red[s][0];
  }
}

// ---------- Kernel 3: values[s,b,v], in-block 4-way f-split ----------
// 1024 threads: part = tid>>8 handles f rows [part*64, +64) + q rows
// [part*8, +8) for c4 tile column lane_c = tid&255. LDS max-combine.
// Inner loops BRANCHLESS (fminf select with +/-INF from LDS), loads
// manually batched 8-deep (round-3 post-mortem: per-f `if` branches
// serialized loads). Raw maxima propagate exactly:
// max(log1p(relu(a)), log1p(relu(b))) == log1p(relu(max(a,b))).
__global__ __launch_bounds__(1024) void k_values(
    const float* __restrict__ q_logits,   // [B,LQ,V]
    const float* __restrict__ f_logits,   // [B,LF,V]
    const float* __restrict__ q_mask,     // [B,LQ]
    const unsigned* __restrict__ actmask, // ws [B,LF]
    float* __restrict__ out)              // d_out base (values at offset 0)
{
  const int b = blockIdx.y;
  const int tid = threadIdx.x;
  const int lane_c = tid & 255;
  const int part = tid >> 8;            // 0..3

  // ssel[s][f] = +INF if action s selects row f else -INF  (fminf select)
  __shared__ float ssel[NS][NLF];
  __shared__ float sqsel[NLQ];
  __shared__ float4 red[NPART - 1][256][NS];   // 48 KB combine buffer
  if (tid < NLF) {
    const unsigned mk = actmask[b * NLF + tid];
#pragma unroll
    for (int s = 0; s < NS; ++s)
      ssel[s][tid] = (mk >> s) & 1u ? INFINITY : -INFINITY;
  }
  if (tid < NLQ)
    sqsel[tid] = (q_mask[b * NLQ + tid] > 0.5f) ? INFINITY : -INFINITY;
  __syncthreads();

  const int c4r = blockIdx.x * 256 + lane_c;   // float4 index within row
  // Clamp instead of early-return: all 1024 threads must reach the
  // combine barriers. Redundant clamped loads hit L2, stores predicated.
  const int c4 = (c4r < NV4) ? c4r : (NV4 - 1);

  const float4* qp = (const float4*)q_logits;
  const float4* fp = (const float4*)f_logits;

  float m[NS][4];
#pragma unroll
  for (int s = 0; s < NS; ++s)
#pragma unroll
    for (int c = 0; c < 4; ++c) m[s][c] = -INFINITY;

  // ---- q share: 8 rows, one 8-deep batch, folded into all samples
  {
    float4 x[8];
#pragma unroll
    for (int j = 0; j < 8; ++j)
      x[j] = qp[(size_t)(b * NLQ + part * QCHUNK + j) * NV4 + c4];
    float qm[4] = {-INFINITY, -INFINITY, -INFINITY, -INFINITY};
#pragma unroll
    for (int j = 0; j < 8; ++j) {
      const float sv = sqsel[part * QCHUNK + j];
      qm[0] = fmaxf(qm[0], fminf(x[j].x, sv));
      qm[1] = fmaxf(qm[1], fminf(x[j].y, sv));
      qm[2] = fmaxf(qm[2], fminf(x[j].z, sv));
      qm[3] = fmaxf(qm[3], fminf(x[j].w, sv));
    }
#pragma unroll
    for (int s = 0; s < NS; ++s)
#pragma unroll
      for (int c = 0; c < 4; ++c) m[s][c] = fmaxf(m[s][c], qm[c]);
  }

  // ---- f share: 64 rows, 8 batches of 8, branchless 4-sample select/max
  for (int f0 = 0; f0 < FCHUNK; f0 += 8) {
    float4 x[8];
#pragma unroll
    for (int j = 0; j < 8; ++j)
      x[j] = fp[(size_t)(b * NLF + part * FCHUNK + f0 + j) * NV4 + c4];
#pragma unroll
    for (int j = 0; j < 8; ++j) {
#pragma unroll
      for (int s = 0; s < NS; ++s) {
        const float sv = ssel[s][part * FCHUNK + f0 + j];
        m[s][0] = fmaxf(m[s][0], fminf(x[j].x, sv));
        m[s][1] = fmaxf(m[s][1], fminf(x[j].y, sv));
        m[s][2] = fmaxf(m[s][2], fminf(x[j].z, sv));
        m[s][3] = fmaxf(m[s][3], fminf(x[j].w, sv));
      }
    }
  }

  // ---- combine the 4 parts via LDS (stride-16 float4 = 2-way alias, free)
  if (part != 0) {
#pragma unroll
    for (int s = 0; s < NS; ++s)
      red[part - 1][lane_c][s] = make_float4(m[s][0], m[s][1], m[s][2], m[s][3]);
  }
  __syncthreads();

  if (part == 0 && c4r < NV4) {
    float4* ov = (float4*)out;
#pragma unroll
    for (int s = 0; s < NS; ++s) {
      float4 mm = make_float4(m[s][0], m[s][1], m[s][2], m[s][3]);
#pragma unroll
      for (int p = 0; p < NPART - 1; ++p) {
        const float4 t = red[p][lane_c][s];
        mm.x = fmaxf(mm.x, t.x);
        mm.y = fmaxf(mm.y, t.y);
        mm.z = fmaxf(mm.z, t.z);
        mm.w = fmaxf(mm.w, t.w);
      }
      float4 r;
      r.x = log1pf(fmaxf(mm.x, 0.f));
      r.y = log1pf(fmaxf(mm.y, 0.f));
      r.z = log1pf(fmaxf(mm.z, 0.f));
      r.w = log1pf(fmaxf(mm.w, 0.f));
      ov[(size_t)(s * NB + b) * NV4 + c4r] = r;
    }
  }
}

extern "C" void kernel_launch(void* const* d_in, const int* in_sizes, int n_in,
                              void* d_out, int out_size, void* d_ws, size_t ws_size,
                              hipStream_t stream) {
  const float* attn_scores = (const float*)d_in[0];
  const float* q_logits    = (const float*)d_in[1];
  const float* f_logits    = (const float*)d_in[2];
  const float* q_mask      = (const float*)d_in[3];
  const float* attn_mask   = (const float*)d_in[4];
  float* out = (float*)d_out;

  float* ws_scores   = (float*)d_ws;                            // B*LQ*LF floats
  unsigned* ws_mask  = (unsigned*)(ws_scores + NB * NLQ * NLF); // B*LF uint32

  k_mean<<<dim3((NB * NLQ * NLF) / 256), 256, 0, stream>>>(attn_scores, ws_scores);
  k_probs<<<dim3(NB), 256, 0, stream>>>(ws_scores, attn_mask, out, ws_mask);
  k_values<<<dim3((NV4 + 255) / 256, NB), 1024, 0, stream>>>(
      q_logits, f_logits, q_mask, ws_mask, out);
}

// Round 4
// 362.281 us; speedup vs baseline: 1.0956x; 1.0832x over previous
//
#include <hip/hip_runtime.h>
#include <stdint.h>

// Problem constants (fixed by reference)
#define NB 8
#define NH 12
#define NLQ 32
#define NLF 256
#define NV 32000
#define NS 4
#define NV4 (NV / 4)   /* 8000 float4 per [b] row */

// d_out layout: values[NS,NB,NV] | logprobs[NS,NB] | actions[NS,NB,NLF]
#define OUT_LOGP (NS * NB * NV)          /* 1024000 */
#define OUT_ACT  (OUT_LOGP + NS * NB)    /* 1024032 */

// Round-4 structure: 2 dispatches (was 3).
//   k_mean  : 256 blocks, head-mean -> ws_scores (full parallelism; an
//             8-block fused variant would run ~10us at 8-CU BW — keep split).
//   k_fused : probs prologue (recomputed per block — threefry is pure, all
//             32 cx-blocks of a batch derive identical masks from the
//             L2-resident 32KB ws_scores slice; no inter-block comm) +
//             the 299MB value stream.
// Evidence: R1 marginal traffic rate 6.1 TB/s (BW-saturated), R3 occupancy
// 4x neutral -> remaining controllable cost is dispatch gaps, not BW.

typedef float f32x4 __attribute__((ext_vector_type(4)));

__device__ __forceinline__ uint32_t rotl32(uint32_t v, int r) {
  return (v << r) | (v >> (32 - r));
}

// Exact JAX threefry2x32 (rotations [13,15,26,6]/[17,29,16,24], 5 key injections)
__device__ __forceinline__ void threefry2x32(uint32_t k0, uint32_t k1,
                                             uint32_t& x0, uint32_t& x1) {
  const uint32_t ks2 = k0 ^ k1 ^ 0x1BD11BDAu;
  x0 += k0; x1 += k1;
#define TF_ROUND(r) { x0 += x1; x1 = rotl32(x1, r); x1 ^= x0; }
  TF_ROUND(13) TF_ROUND(15) TF_ROUND(26) TF_ROUND(6)
  x0 += k1; x1 += ks2 + 1u;
  TF_ROUND(17) TF_ROUND(29) TF_ROUND(16) TF_ROUND(24)
  x0 += ks2; x1 += k0 + 2u;
  TF_ROUND(13) TF_ROUND(15) TF_ROUND(26) TF_ROUND(6)
  x0 += k0; x1 += k1 + 3u;
  TF_ROUND(17) TF_ROUND(29) TF_ROUND(16) TF_ROUND(24)
  x0 += k1; x1 += ks2 + 4u;
  TF_ROUND(13) TF_ROUND(15) TF_ROUND(26) TF_ROUND(6)
  x0 += ks2; x1 += k0 + 5u;
#undef TF_ROUND
}

// ---------- Kernel 1: mean over heads -> ws_scores[B,LQ,LF] ----------
__global__ __launch_bounds__(256) void k_mean(const float* __restrict__ as,
                                              float* __restrict__ scores) {
  const int o = blockIdx.x * 256 + threadIdx.x;   // [0, 65536)
  const int f  = o & (NLF - 1);
  const int lq = (o >> 8) & (NLQ - 1);
  const int b  = o >> 13;
  float s = 0.f;
#pragma unroll
  for (int h = 0; h < NH; ++h)
    s += as[(((size_t)(b * NH + h) * NLQ) + lq) * NLF + f];
  scores[o] = s / 12.0f;
}

// ---------- Kernel 2: fused probs-prologue + value stream ----------
// grid (32, NB) x 256 threads = 256 blocks = 1/CU. Thread f = lane_c.
// Prologue (every block): agg/sigmoid/threefry for column f of batch b ->
// ssel/sqsel in LDS. cx==0 additionally writes actions + logprob tree
// (identical FP op order to the old k_probs -> bit-exact).
// Stream: BRANCHLESS select (fminf with +/-INF), 16-deep nontemporal load
// batches (zero-reuse data; keeps ws_scores L2-resident for prologue reuse).
// Raw maxima propagate exactly: max(log1p(relu(a)),log1p(relu(b))) ==
// log1p(relu(max(a,b))).
__global__ __launch_bounds__(256, 1) void k_fused(
    const float* __restrict__ scores,     // ws [B,LQ,LF]
    const float* __restrict__ attn_mask,  // [B,LF]
    const float* __restrict__ q_logits,   // [B,LQ,V]
    const float* __restrict__ f_logits,   // [B,LF,V]
    const float* __restrict__ q_mask,     // [B,LQ]
    float* __restrict__ out)              // d_out base
{
  const int b  = blockIdx.y;
  const int cx = blockIdx.x;
  const int f  = threadIdx.x;

  __shared__ float ssel[NS][NLF];   // +INF if action s selects row f else -INF
  __shared__ float sqsel[NLQ];
  __shared__ float red[NS][NLF];    // logprob tree (cx==0 only)

  // ---- probs prologue (all blocks; deterministic recompute) ----
  float agg = -INFINITY;
#pragma unroll
  for (int lq = 0; lq < NLQ; ++lq)
    agg = fmaxf(agg, scores[(b * NLQ + lq) * NLF + f]);

  const float amask = attn_mask[b * NLF + f];
  const float p = amask * (1.0f / (1.0f + expf(-agg)));   // sigmoid * mask
  const float lp  = logf(p);
  const float l1p = log1pf(-p);

  float terms[NS];
#pragma unroll
  for (int s = 0; s < NS; ++s) {
    bool act;
    if (s < NS - 1) {
      // JAX partitionable threefry 32-bit bits: counter n,
      // (o0,o1) = threefry2x32(key, hi(n)=0, lo(n)=n); bits = o0 ^ o1
      const uint32_t n = (uint32_t)(s * (NB * NLF) + b * NLF + f);
      uint32_t x0 = 0u, x1 = n;
      threefry2x32(0u, 42u, x0, x1);
      const uint32_t bits = x0 ^ x1;
      const float u = __uint_as_float((bits >> 9) | 0x3f800000u) - 1.0f;
      act = (u < p);
    } else {
      act = (p >= 0.5f);
    }
    ssel[s][f] = act ? INFINITY : -INFINITY;
    terms[s] = act ? lp : l1p;
    if (cx == 0) out[OUT_ACT + (s * NB + b) * NLF + f] = act ? 1.0f : 0.0f;
  }
  if (f < NLQ)
    sqsel[f] = (q_mask[b * NLQ + f] > 0.5f) ? INFINITY : -INFINITY;
  if (cx == 0) {
#pragma unroll
    for (int s = 0; s < NS; ++s) red[s][f] = terms[s];
  }
  __syncthreads();

  if (cx == 0) {   // uniform per block -> barriers legal
    for (int off = 128; off > 0; off >>= 1) {
      if (f < off) {
#pragma unroll
        for (int s = 0; s < NS; ++s) red[s][f] += red[s][f + off];
      }
      __syncthreads();
    }
    if (f == 0) {
#pragma unroll
      for (int s = 0; s < NS; ++s) out[OUT_LOGP + s * NB + b] = red[s][0];
    }
  }

  // ---- value stream ----
  const int c4 = cx * 256 + f;     // float4 index within row
  if (c4 >= NV4) return;           // only cx==31 partial; no barriers follow
                                   // (cx==0 threads all have c4 < 256 < NV4)

  const f32x4* qp = (const f32x4*)q_logits;
  const f32x4* fp = (const f32x4*)f_logits;
  const f32x4 NEGINF4 = {-INFINITY, -INFINITY, -INFINITY, -INFINITY};

  // q part: raw masked max; log1p(relu) applied once at the end.
  f32x4 qm = NEGINF4;
  for (int l0 = 0; l0 < NLQ; l0 += 16) {
    f32x4 x[16];
#pragma unroll
    for (int j = 0; j < 16; ++j)
      x[j] = __builtin_nontemporal_load(
          &qp[(size_t)(b * NLQ + l0 + j) * NV4 + c4]);
#pragma unroll
    for (int j = 0; j < 16; ++j) {
      const float sv = sqsel[l0 + j];
#pragma unroll
      for (int c = 0; c < 4; ++c)
        qm[c] = fmaxf(qm[c], fminf(x[j][c], sv));
    }
  }
  float qlog[4];
#pragma unroll
  for (int c = 0; c < 4; ++c) qlog[c] = log1pf(fmaxf(qm[c], 0.f));

  // f part: 4 masked raw maxes, 16 batches of 16 rows, branchless.
  f32x4 m[NS];
#pragma unroll
  for (int s = 0; s < NS; ++s) m[s] = NEGINF4;

  for (int f0 = 0; f0 < NLF; f0 += 16) {
    f32x4 x[16];
#pragma unroll
    for (int j = 0; j < 16; ++j)
      x[j] = __builtin_nontemporal_load(
          &fp[(size_t)(b * NLF + f0 + j) * NV4 + c4]);
#pragma unroll
    for (int j = 0; j < 16; ++j) {
#pragma unroll
      for (int s = 0; s < NS; ++s) {
        const float sv = ssel[s][f0 + j];
#pragma unroll
        for (int c = 0; c < 4; ++c)
          m[s][c] = fmaxf(m[s][c], fminf(x[j][c], sv));
      }
    }
  }

  f32x4* ov = (f32x4*)out;
#pragma unroll
  for (int s = 0; s < NS; ++s) {
    f32x4 r;
#pragma unroll
    for (int c = 0; c < 4; ++c)
      r[c] = fmaxf(qlog[c], log1pf(fmaxf(m[s][c], 0.f)));
    __builtin_nontemporal_store(r, &ov[(size_t)(s * NB + b) * NV4 + c4]);
  }
}

extern "C" void kernel_launch(void* const* d_in, const int* in_sizes, int n_in,
                              void* d_out, int out_size, void* d_ws, size_t ws_size,
                              hipStream_t stream) {
  const float* attn_scores = (const float*)d_in[0];
  const float* q_logits    = (const float*)d_in[1];
  const float* f_logits    = (const float*)d_in[2];
  const float* q_mask      = (const float*)d_in[3];
  const float* attn_mask   = (const float*)d_in[4];
  float* out = (float*)d_out;

  float* ws_scores = (float*)d_ws;   // B*LQ*LF floats (only ws use)

  k_mean<<<dim3((NB * NLQ * NLF) / 256), 256, 0, stream>>>(attn_scores, ws_scores);
  k_fused<<<dim3((NV4 + 255) / 256, NB), 256, 0, stream>>>(
      ws_scores, attn_mask, q_logits, f_logits, q_mask, out);
}